// Round 8
// baseline (368.726 us; speedup 1.0000x reference)
//
#include <hip/hip_runtime.h>
#include <cstddef>

#define NN 100000
#define NE 3200000
#define FIN 128
#define HID 16
#define NC 40
#define NBUK 196                 // ceil(100000 / 512) node-range buckets
#define CHUNK 4096               // edges per block in bucketing passes
#define NBLK_BKT ((NE + CHUNK - 1) / CHUNK)   // 782
#define NWAVE_G1 (NN / 16)       // 6250 waves, 16 nodes each
#define NBLK_G1 ((NWAVE_G1 + 3) / 4)          // 1563

typedef __attribute__((ext_vector_type(8))) short bf16x8;
typedef __attribute__((ext_vector_type(4))) float f32x4;

// ---- bf16 helpers (RNE pack, cheap unpack) ----
__device__ __forceinline__ unsigned bf16rne(float f) {
  unsigned u = __float_as_uint(f);
  return (u + 0x7fffu + ((u >> 16) & 1u)) >> 16;
}
__device__ __forceinline__ unsigned bfpack(float lo, float hi) {
  return bf16rne(lo) | (bf16rne(hi) << 16);
}
__device__ __forceinline__ float bflo(unsigned w) { return __uint_as_float(w << 16); }
__device__ __forceinline__ float bfhi(unsigned w) { return __uint_as_float(w & 0xffff0000u); }

// ---------- CSR build: bucketed counting sort (atomic-light) ----------

__global__ __launch_bounds__(256) void k_bcount(const int* __restrict__ ei,
                                                int* __restrict__ bcnt) {
  __shared__ int h[NBUK];
  int t = threadIdx.x;
  for (int i = t; i < NBUK; i += 256) h[i] = 0;
  __syncthreads();
  int base = blockIdx.x * CHUNK;
#pragma unroll
  for (int i = 0; i < 16; ++i) {
    int e = base + i * 256 + t;
    if (e < NE) atomicAdd(&h[ei[NE + e] >> 9], 1);
  }
  __syncthreads();
  for (int i = t; i < NBUK; i += 256)
    if (h[i]) atomicAdd(&bcnt[i], h[i]);
}

__global__ __launch_bounds__(256) void k_bscan(const int* __restrict__ bcnt,
    int* __restrict__ bbase, int* __restrict__ bcur) {
  __shared__ int scn[256];
  int t = threadIdx.x;
  int v = (t < NBUK) ? bcnt[t] : 0;
  scn[t] = v;
  __syncthreads();
  for (int st = 1; st < 256; st <<= 1) {
    int tmp = (t >= st) ? scn[t - st] : 0;
    __syncthreads();
    scn[t] += tmp;
    __syncthreads();
  }
  if (t < NBUK) { int ex = scn[t] - v; bbase[t] = ex; bcur[t] = ex; }
  if (t == NBUK - 1) bbase[NBUK] = scn[t];
}

// Record: .x = (dst&511)<<17 | src   (src < 2^17), .y = bits(u)
__global__ __launch_bounds__(256) void k_bucketize(const int* __restrict__ ei,
    const float* __restrict__ ea, int* __restrict__ bcur,
    int2* __restrict__ bstream) {
  __shared__ int lh[NBUK];
  __shared__ int lbase[NBUK];
  __shared__ int gb[NBUK];
  __shared__ int scn[256];
  __shared__ int meta[CHUNK];
  __shared__ int uval[CHUNK];
  __shared__ unsigned char sbkt[CHUNK];
  int t = threadIdx.x;
  for (int i = t; i < NBUK; i += 256) lh[i] = 0;
  __syncthreads();
  int base = blockIdx.x * CHUNK;
  int rk[16], bk[16], mt[16], uv[16];
#pragma unroll
  for (int i = 0; i < 16; ++i) {
    int e = base + i * 256 + t;
    if (e < NE) {
      int d = ei[NE + e], sv = ei[e];
      int b = d >> 9;
      rk[i] = atomicAdd(&lh[b], 1);
      bk[i] = b;
      mt[i] = ((d & 511) << 17) | sv;
      uv[i] = __float_as_int(ea[e]);
    } else bk[i] = -1;
  }
  __syncthreads();
  int v = (t < NBUK) ? lh[t] : 0;
  scn[t] = v;
  __syncthreads();
  for (int st = 1; st < 256; st <<= 1) {
    int tmp = (t >= st) ? scn[t - st] : 0;
    __syncthreads();
    scn[t] += tmp;
    __syncthreads();
  }
  if (t < NBUK) lbase[t] = scn[t] - v;
  int total = scn[255];
  __syncthreads();
  if (t < NBUK && lh[t] > 0) gb[t] = atomicAdd(&bcur[t], lh[t]);
  __syncthreads();
#pragma unroll
  for (int i = 0; i < 16; ++i) {
    if (bk[i] >= 0) {
      int p = lbase[bk[i]] + rk[i];
      meta[p] = mt[i];
      uval[p] = uv[i];
      sbkt[p] = (unsigned char)bk[i];
    }
  }
  __syncthreads();
  for (int s = t; s < total; s += 256) {
    int b = sbkt[s];
    bstream[gb[b] + (s - lbase[b])] = make_int2(meta[s], uval[s]);
  }
}

// Pass D: one block per bucket -> off[] + packed sedge (src | u15<<17)
__global__ __launch_bounds__(512) void k_csr(const int2* __restrict__ bstream,
    const int* __restrict__ bbase, int* __restrict__ off,
    unsigned* __restrict__ sedge) {
  __shared__ int cnt[512];
  __shared__ int scn[512];
  __shared__ int cur[512];
  int b = blockIdx.x, t = threadIdx.x;
  int s0 = bbase[b], s1 = bbase[b + 1];
  cnt[t] = 0;
  __syncthreads();
  for (int i = s0 + t; i < s1; i += 512)
    atomicAdd(&cnt[bstream[i].x >> 17], 1);
  __syncthreads();
  int v = cnt[t];
  scn[t] = v;
  __syncthreads();
  for (int st = 1; st < 512; st <<= 1) {
    int tmp = (t >= st) ? scn[t - st] : 0;
    __syncthreads();
    scn[t] += tmp;
    __syncthreads();
  }
  int n = (b << 9) + t;
  if (n < NN) off[n] = s0 + scn[t];          // inclusive row-end
  cur[t] = s0 + scn[t] - v;                  // row start cursor
  __syncthreads();
  for (int i = s0 + t; i < s1; i += 512) {
    int2 r = bstream[i];
    int local = r.x >> 17;
    int pos = atomicAdd(&cur[local], 1);
    unsigned u15 = (unsigned)__float2int_rn(__int_as_float(r.y) * 32767.0f);
    sedge[pos] = (unsigned)(r.x & 131071) | (u15 << 17);
  }
}

// ---------- dense / pull kernels ----------

// K1 (MFMA): one wave computes 16 nodes x 48 cols of x @ [W1[0]|W1[1]|root1].
// Epilogue splits XD into two half-tables (3.2 MB each) for L2-resident pulls.
__global__ __launch_bounds__(256) void k_gemm1(const float* __restrict__ x,
    const float* __restrict__ W1, const float* __restrict__ root1,
    const float* __restrict__ bias1,
    unsigned* __restrict__ XDa, unsigned* __restrict__ XDb,
    float* __restrict__ XR) {
  int t = threadIdx.x;
  int l = t & 63;
  int wv = (blockIdx.x * 256 + t) >> 6;
  int nb = wv * 16;
  if (nb >= NN) return;
  int j16 = l & 15, kg = l >> 4;

  bf16x8 bfrag[3][4];
  const float* wsrc0 = W1;
  const float* wsrc1 = W1 + 2048;
  const float* wsrc2 = root1;
#pragma unroll
  for (int kk = 0; kk < 4; ++kk) {
    int krow = kk * 32 + kg * 8;
#pragma unroll
    for (int b = 0; b < 8; ++b) {
      int o = (krow + b) * 16 + j16;
      bfrag[0][kk][b] = (short)bf16rne(wsrc0[o]);
      bfrag[1][kk][b] = (short)bf16rne(wsrc1[o]);
      bfrag[2][kk][b] = (short)bf16rne(wsrc2[o]);
    }
  }

  f32x4 acc0 = {0.f, 0.f, 0.f, 0.f};
  f32x4 acc1 = {0.f, 0.f, 0.f, 0.f};
  f32x4 acc2 = {0.f, 0.f, 0.f, 0.f};
  const float* xrow = x + (size_t)(nb + j16) * FIN + kg * 8;
#pragma unroll
  for (int kk = 0; kk < 4; ++kk) {
    float4 xa = *(const float4*)(xrow + kk * 32);
    float4 xb = *(const float4*)(xrow + kk * 32 + 4);
    bf16x8 a;
    a[0] = (short)bf16rne(xa.x); a[1] = (short)bf16rne(xa.y);
    a[2] = (short)bf16rne(xa.z); a[3] = (short)bf16rne(xa.w);
    a[4] = (short)bf16rne(xb.x); a[5] = (short)bf16rne(xb.y);
    a[6] = (short)bf16rne(xb.z); a[7] = (short)bf16rne(xb.w);
    acc0 = __builtin_amdgcn_mfma_f32_16x16x32_bf16(a, bfrag[0][kk], acc0, 0, 0, 0);
    acc1 = __builtin_amdgcn_mfma_f32_16x16x32_bf16(a, bfrag[1][kk], acc1, 0, 0, 0);
    acc2 = __builtin_amdgcn_mfma_f32_16x16x32_bf16(a, bfrag[2][kk], acc2, 0, 0, 0);
  }

  float bb = bias1[j16];
#pragma unroll
  for (int r = 0; r < 4; ++r) {
    int n = nb + kg * 4 + r;
    unsigned pk = bfpack(acc0[r], acc1[r] - acc0[r]);
    if (j16 < 8) XDa[(size_t)n * 8 + j16] = pk;
    else         XDb[(size_t)n * 8 + (j16 - 8)] = pk;
    XR[(size_t)n * HID + j16] = acc2[r] + bb;
  }
}

// Pull pass 1, one channel-half per launch. Gathers hit a 3.2 MB table
// (L2-resident per XCD). 2 threads/node, 4 channels each.
template <int HALF>
__global__ __launch_bounds__(256) void k_pull1h(const int* __restrict__ off,
    const unsigned* __restrict__ sedge, const unsigned* __restrict__ XDh,
    const float* __restrict__ XR, unsigned* __restrict__ Hb) {
  int tid = blockIdx.x * 256 + threadIdx.x;
  int n = tid >> 1, c = tid & 1;
  if (n >= NN) return;
  int start = (n == 0) ? 0 : off[n - 1];
  int end = off[n];
  float4 acc = make_float4(0.f, 0.f, 0.f, 0.f);
  for (int i = start; i < end; ++i) {
    unsigned se = __builtin_nontemporal_load(&sedge[i]);
    int s = se & 131071u;
    float u = (float)(se >> 17) * (1.0f / 32767.0f);
    uint4 w = *(const uint4*)(XDh + (size_t)s * 8 + c * 4);
    acc.x += bflo(w.x) + u * bfhi(w.x);
    acc.y += bflo(w.y) + u * bfhi(w.y);
    acc.z += bflo(w.z) + u * bfhi(w.z);
    acc.w += bflo(w.w) + u * bfhi(w.w);
  }
  float ic = 1.0f / fmaxf((float)(end - start), 1.0f);
  float4 r = *(const float4*)(XR + (size_t)n * HID + HALF * 8 + c * 4);
  float4 h;
  h.x = acc.x * ic + r.x;
  h.y = acc.y * ic + r.y;
  h.z = acc.z * ic + r.z;
  h.w = acc.w * ic + r.w;
  h.x = h.x > 0.f ? h.x : expm1f(h.x);
  h.y = h.y > 0.f ? h.y : expm1f(h.y);
  h.z = h.z > 0.f ? h.z : expm1f(h.z);
  h.w = h.w > 0.f ? h.w : expm1f(h.w);
  uint2 hw;
  hw.x = bfpack(h.x, h.y);
  hw.y = bfpack(h.z, h.w);
  *(uint2*)(Hb + (size_t)n * 8 + HALF * 4 + c * 2) = hw;
}

// Pull pass 2: A0[n] = sum (1-u)*H[s];  A1[n] = sum u*H[s]   (f32 out)
__global__ __launch_bounds__(256) void k_pull2(const int* __restrict__ off,
    const unsigned* __restrict__ sedge, const unsigned* __restrict__ Hb,
    float* __restrict__ A0, float* __restrict__ A1) {
  int tid = blockIdx.x * 256 + threadIdx.x;
  int n = tid >> 2, c = tid & 3;
  if (n >= NN) return;
  int start = (n == 0) ? 0 : off[n - 1];
  int end = off[n];
  float4 a0 = make_float4(0.f, 0.f, 0.f, 0.f);
  float4 a1 = make_float4(0.f, 0.f, 0.f, 0.f);
  for (int i = start; i < end; ++i) {
    unsigned se = __builtin_nontemporal_load(&sedge[i]);
    int s = se & 131071u;
    float u = (float)(se >> 17) * (1.0f / 32767.0f);
    uint2 w = *(const uint2*)(Hb + (size_t)s * 8 + c * 2);
    float h0 = bflo(w.x), h1 = bfhi(w.x), h2 = bflo(w.y), h3 = bfhi(w.y);
    a0.x += h0 - u * h0;  a1.x += u * h0;
    a0.y += h1 - u * h1;  a1.y += u * h1;
    a0.z += h2 - u * h2;  a1.z += u * h2;
    a0.w += h3 - u * h3;  a1.w += u * h3;
  }
  *(float4*)(A0 + (size_t)n * HID + c * 4) = a0;
  *(float4*)(A1 + (size_t)n * HID + c * 4) = a1;
}

// K5: out = log_softmax( (A0@W2[0] + A1@W2[1])/max(deg,1) + H@root2 + bias2 )
__global__ __launch_bounds__(256) void k_final(const float* __restrict__ A0,
    const float* __restrict__ A1, const unsigned* __restrict__ Hb,
    const int* __restrict__ off, const float* __restrict__ W2,
    const float* __restrict__ root2, const float* __restrict__ bias2,
    float* __restrict__ out) {
  int t = threadIdx.x;
  int l = t & 63;
  int j = (l < NC) ? l : 0;
  float w0r[HID], w1r[HID], rr[HID];
#pragma unroll
  for (int k = 0; k < HID; ++k) {
    w0r[k] = W2[k * NC + j];
    w1r[k] = W2[HID * NC + k * NC + j];
    rr[k]  = root2[k * NC + j];
  }
  float b2 = bias2[j];
  int wid = (blockIdx.x * 256 + t) >> 6;
  int nwaves = gridDim.x * 4;
  for (int n0 = wid; n0 < NN; n0 += nwaves) {
    int n = __builtin_amdgcn_readfirstlane(n0);
    const float* a0p = A0 + (size_t)n * HID;
    const float* a1p = A1 + (size_t)n * HID;
    const unsigned* hp = Hb + (size_t)n * 8;
    int e1 = off[n];
    int e0 = (n == 0) ? 0 : off[n - 1];
    float ic = 1.0f / fmaxf((float)(e1 - e0), 1.0f);
    float accm = 0.f, accr = 0.f;
#pragma unroll
    for (int k = 0; k < HID; ++k) {
      accm += a0p[k] * w0r[k];
      accm += a1p[k] * w1r[k];
      unsigned hw = hp[k >> 1];
      float hk = (k & 1) ? bfhi(hw) : bflo(hw);
      accr += hk * rr[k];
    }
    float logit = accm * ic + accr + b2;
    float mx = (l < NC) ? logit : -INFINITY;
#pragma unroll
    for (int o = 32; o >= 1; o >>= 1) mx = fmaxf(mx, __shfl_xor(mx, o));
    float p = (l < NC) ? __expf(logit - mx) : 0.f;
    float sm = p;
#pragma unroll
    for (int o = 32; o >= 1; o >>= 1) sm += __shfl_xor(sm, o);
    if (l < NC) out[(size_t)n * NC + l] = logit - mx - __logf(sm);
  }
}

extern "C" void kernel_launch(void* const* d_in, const int* in_sizes, int n_in,
                              void* d_out, int out_size, void* d_ws, size_t ws_size,
                              hipStream_t stream) {
  const float* x     = (const float*)d_in[0];
  const int*   ei    = (const int*)d_in[1];
  const float* ea    = (const float*)d_in[2];
  const float* W1    = (const float*)d_in[3];
  const float* root1 = (const float*)d_in[4];
  const float* bias1 = (const float*)d_in[5];
  const float* W2    = (const float*)d_in[6];
  const float* root2 = (const float*)d_in[7];
  const float* bias2 = (const float*)d_in[8];
  float* out = (float*)d_out;
  char* base = (char*)d_ws;

  // Layout (bytes):
  //   [0,       3.2M)  XDa (u32[NN*8], bf16 X0|D ch0-7)   \ -> later A0 (f32[NN*16])
  //   [3.2M,    6.4M)  XDb (u32[NN*8], bf16 X0|D ch8-15)  /
  //   [6.4M,   12.8M)  XR  (f32[NN*16])                   -> later A1 (f32[NN*16])
  //   [12.8M,  16.0M)  Hb  (u32[NN*8],  bf16 H pairs)
  //   [0,      25.6M)  bstream (int2[NE]) during CSR build only (dead before k_gemm1)
  //   [25.6M,  38.4M)  sedge (u32[NE], src|u15<<17)
  //   [38.4M, ...)     off[NN], bcnt, bbase, bcur
  unsigned* XDa = (unsigned*)base;
  unsigned* XDb = (unsigned*)(base + 3200000);
  float*    XR = (float*)(base + 6400000);
  unsigned* Hb = (unsigned*)(base + 12800000);
  float*    A0 = (float*)base;
  float*    A1 = (float*)(base + 6400000);
  int2*     bstream = (int2*)base;
  unsigned* sedge = (unsigned*)(base + 25600000);
  int*      off   = (int*)(base + 38400000);
  int*      bcnt  = off + NN;
  int*      bbase = bcnt + NBUK;
  int*      bcur  = bbase + NBUK + 1;

  hipMemsetAsync(bcnt, 0, NBUK * sizeof(int), stream);

  // CSR build first (bstream aliases node tables)
  k_bcount<<<NBLK_BKT, 256, 0, stream>>>(ei, bcnt);
  k_bscan<<<1, 256, 0, stream>>>(bcnt, bbase, bcur);
  k_bucketize<<<NBLK_BKT, 256, 0, stream>>>(ei, ea, bcur, bstream);
  k_csr<<<NBUK, 512, 0, stream>>>(bstream, bbase, off, sedge);

  // Dense + pulls
  k_gemm1<<<NBLK_G1, 256, 0, stream>>>(x, W1, root1, bias1, XDa, XDb, XR);
  k_pull1h<0><<<(NN * 2 + 255) / 256, 256, 0, stream>>>(off, sedge, XDa, XR, Hb);
  k_pull1h<1><<<(NN * 2 + 255) / 256, 256, 0, stream>>>(off, sedge, XDb, XR, Hb);
  k_pull2<<<(NN * 4 + 255) / 256, 256, 0, stream>>>(off, sedge, Hb, A0, A1);
  k_final<<<1024, 256, 0, stream>>>(A0, A1, Hb, off, W2, root2, bias2, out);
}